// Round 17
// baseline (548.588 us; speedup 1.0000x reference)
//
#include <hip/hip_runtime.h>
#include <stdint.h>
#include <string.h>

typedef unsigned short u16;
typedef __attribute__((ext_vector_type(8))) short short8_t;   // 8 x bf16 (4 VGPRs)
typedef __attribute__((ext_vector_type(4))) float f32x4;

typedef const __attribute__((address_space(1))) void GV;
typedef __attribute__((address_space(3))) void LV;

__device__ __forceinline__ void gload_lds16(const void* g, void* l) {
  // async global->LDS, 16B per lane; LDS dest is wave-uniform base + lane*16
  __builtin_amdgcn_global_load_lds((GV*)g, (LV*)l, 16, 0, 0);
}

__device__ __forceinline__ u16 f2bf(float f) {
  union { float f; uint32_t u; } v; v.f = f;
  return (u16)((v.u + 0x7FFFu + ((v.u >> 16) & 1u)) >> 16);  // RNE
}

__device__ __forceinline__ f32x4 fz4() { f32x4 v = {0.f, 0.f, 0.f, 0.f}; return v; }

// ------------- all casts fp32 -> bf16 (4 elems/thread) in ONE launch -------------
__global__ __launch_bounds__(256) void cast_all(const float* __restrict__ x,
                                                const float* __restrict__ y,
                                                const float* __restrict__ w0,
                                                const float* __restrict__ w1,
                                                const float* __restrict__ w2,
                                                const float* __restrict__ w3,
                                                u16* __restrict__ xo,
                                                u16* __restrict__ yo,
                                                u16* __restrict__ o0,
                                                u16* __restrict__ o1,
                                                u16* __restrict__ o2,
                                                u16* __restrict__ o3) {
  const int bid = blockIdx.x;
  const float* in;
  u16* out;
  int off;
  if (bid < 32768) {
    in = (bid < 16384) ? x : y;
    out = (bid < 16384) ? xo : yo;
    off = bid & 16383;
  } else {
    const int s = (bid - 32768) >> 10;
    in = s == 0 ? w0 : s == 1 ? w1 : s == 2 ? w2 : w3;
    out = s == 0 ? o0 : s == 1 ? o1 : s == 2 ? o2 : o3;
    off = (bid - 32768) & 1023;
  }
  int i = (off * 256 + threadIdx.x) * 4;
  float4 v = *(const float4*)(in + i);
  ushort4 o;
  o.x = f2bf(v.x); o.y = f2bf(v.y); o.z = f2bf(v.z); o.w = f2bf(v.w);
  *(ushort4*)(out + i) = o;
}

// ======== 256x256 8-phase GEMM core (T2+T3+T4+T5): C = A[M,K]*B[N,K]^T + bias ========
// R14 EXACT core (measured best). R11 T1 mapping: xcd=bid&7, n fastest, contiguous
// 8-m-tile range per XCD. Per-mode COLUMN PERMUTATION for vector epilogue stores:
//  MODE 0/1 linear: phys(u) = n0 + (u&0xC0) + (u&15)*4 + ((u>>4)&3)
//  MODE 2 VT[hb][d][t]: phys(u) = ((u>>4)&3)*256 + nt*64 + ((u>>6)&3)*16 + (u&15)
template <int MODE>
__device__ __forceinline__ void gemm8_core(int bid, const u16* __restrict__ A,
                                           const u16* __restrict__ B,
                                           const float* __restrict__ bias,
                                           void* __restrict__ Cout,
                                           u16* Al, u16* Bl) {
  const int N = 1024, K = 1024;
  const int tid = threadIdx.x, w = tid >> 6, l = tid & 63;
  const int g = l >> 4, q = l & 15;
  const int xcd = bid & 7;
  const int nt = (bid >> 3) & 3;                 // n fastest within XCD
  const int mt = xcd * 8 + (bid >> 5);           // contiguous m-range per XCD
  const int n0 = nt * 256, m0 = mt * 256;
  const int NT = K >> 6;
  const int ah = w >> 2;            // this wave's A half
  const int bh = (w & 3) >> 1;      // this wave's B half
  const int brow0 = ((w & 3) & 1) * 64;

  // logical B row u (0..255) -> physical B row (column of C)
#define BROW(u)                                                                   \
  (MODE == 2 ? ((((u) >> 4) & 3) * 256 + nt * 64 + (((u) >> 6) & 3) * 16 + ((u) & 15)) \
             : (n0 + (((u) & 0xC0) | (((u) & 15) << 2) | (((u) >> 4) & 3))))

#define STAGE_A(S, half)                                                          \
  {                                                                               \
    _Pragma("unroll") for (int j_ = 0; j_ < 2; ++j_) {                            \
      const int idx_ = j_ * 512 + tid;                                            \
      const int row_ = idx_ >> 3;                                                 \
      const int sl_ = (idx_ & 7) ^ (((idx_ >> 5) & 1) << 1);                      \
      gload_lds16(A + (size_t)(m0 + (half) * 128 + row_) * K + (S) * 64 + sl_ * 8,\
                  Al + ((S) & 1) * 16384 + (half) * 8192 + (j_ * 512 + w * 64) * 8);\
    }                                                                             \
  }
#define STAGE_B(S, half)                                                          \
  {                                                                               \
    _Pragma("unroll") for (int j_ = 0; j_ < 2; ++j_) {                            \
      const int idx_ = j_ * 512 + tid;                                            \
      const int row_ = idx_ >> 3;                                                 \
      const int sl_ = (idx_ & 7) ^ (((idx_ >> 5) & 1) << 1);                      \
      const int pr_ = BROW((half) * 128 + row_);                                  \
      gload_lds16(B + (size_t)pr_ * K + (S) * 64 + sl_ * 8,                       \
                  Bl + ((S) & 1) * 16384 + (half) * 8192 + (j_ * 512 + w * 64) * 8);\
    }                                                                             \
  }

  f32x4 acc[8][4];
#pragma unroll
  for (int i = 0; i < 8; ++i)
#pragma unroll
    for (int n = 0; n < 4; ++n) acc[i][n] = fz4();

  // bias per lane (epilogue operand), load early; index = physical column
  const int wc = (w & 3) * 64;
  float bv[4];
#pragma unroll
  for (int nf = 0; nf < 4; ++nf) bv[nf] = bias[BROW(wc + nf * 16 + q)];

  // prologue: stage tiles 0 and 1 fully (16 loads/thread)
  STAGE_A(0, 0); STAGE_A(0, 1); STAGE_B(0, 0); STAGE_B(0, 1);
  STAGE_A(1, 0); STAGE_A(1, 1); STAGE_B(1, 0); STAGE_B(1, 1);
  asm volatile("s_waitcnt vmcnt(8)");          // tile 0 landed; tile 1 in flight
  __builtin_amdgcn_s_barrier();

  short8_t bfr[4][2];
  for (int S = 0; S < NT; ++S) {
    const int bs = (S & 1) * 16384;
#pragma unroll
    for (int p = 0; p < 4; ++p) {
      // ---- ds_read register subtiles ----
      short8_t afr[2][2];
#pragma unroll
      for (int mi = 0; mi < 2; ++mi)
#pragma unroll
        for (int kk = 0; kk < 2; ++kk) {
          const int r = (2 * p + mi) * 16 + q;
          afr[mi][kk] = *(const short8_t*)(Al + bs + ah * 8192 + r * 64 +
                                           ((kk * 4 + g) ^ (((r >> 2) & 1) << 1)) * 8);
        }
      if (p == 0) {
#pragma unroll
        for (int nf = 0; nf < 4; ++nf)
#pragma unroll
          for (int kk = 0; kk < 2; ++kk) {
            const int r = brow0 + nf * 16 + q;
            bfr[nf][kk] = *(const short8_t*)(Bl + bs + bh * 8192 + r * 64 +
                                             ((kk * 4 + g) ^ (((r >> 2) & 1) << 1)) * 8);
          }
      }
      // ---- issue one half-tile stage ----
      if (p == 0 && S >= 1 && S + 1 < NT) STAGE_A(S + 1, 0);
      if (p == 1 && S >= 1 && S + 1 < NT) STAGE_A(S + 1, 1);
      if (p == 2 && S + 2 < NT) STAGE_B(S + 2, 0);
      if (p == 3 && S + 2 < NT) STAGE_B(S + 2, 1);
      // ---- counted vmcnt once per K-tile, fencing tile S+1's reads ----
      if (p == 3) {
        if (S == NT - 2) { asm volatile("s_waitcnt vmcnt(0)"); }
        else if (S < NT - 2) { asm volatile("s_waitcnt vmcnt(4)"); }
      }
      __builtin_amdgcn_s_barrier();
      asm volatile("s_waitcnt lgkmcnt(0)" ::: "memory");
      __builtin_amdgcn_sched_barrier(0);
      __builtin_amdgcn_s_setprio(1);
#pragma unroll
      for (int nf = 0; nf < 4; ++nf)
#pragma unroll
        for (int mi = 0; mi < 2; ++mi)
#pragma unroll
          for (int kk = 0; kk < 2; ++kk)
            acc[2 * p + mi][nf] = __builtin_amdgcn_mfma_f32_16x16x32_bf16(
                afr[mi][kk], bfr[nf][kk], acc[2 * p + mi][nf], 0, 0, 0);
      __builtin_amdgcn_s_setprio(0);
      __builtin_amdgcn_s_barrier();
    }
  }
#undef STAGE_A
#undef STAGE_B
#undef BROW

  // epilogue: bias + VECTOR stores (C/D: col=lane&15, row=(lane>>4)*4+j)
  const int wr = (w >> 2) * 128;
  if (MODE == 2) {
    const int dvt = nt * 64 + (w & 3) * 16 + q;   // d index (c&255)
#pragma unroll
    for (int mf = 0; mf < 8; ++mf) {
#pragma unroll
      for (int j = 0; j < 4; ++j) {
        const int row = m0 + wr + mf * 16 + g * 4 + j;
        ushort4 st;
        st.x = f2bf(acc[mf][0][j] + bv[0]);
        st.y = f2bf(acc[mf][1][j] + bv[1]);
        st.z = f2bf(acc[mf][2][j] + bv[2]);
        st.w = f2bf(acc[mf][3][j] + bv[3]);
        *(ushort4*)((u16*)Cout + (((size_t)(row >> 8)) << 18) +
                    (((size_t)dvt) << 10) + ((row & 255) << 2)) = st;
      }
    }
  } else {
    const int colb = n0 + wc + q * 4;             // 4 consecutive physical cols
#pragma unroll
    for (int mf = 0; mf < 8; ++mf) {
#pragma unroll
      for (int j = 0; j < 4; ++j) {
        const int row = m0 + wr + mf * 16 + g * 4 + j;
        if (MODE == 0) {
          float4 fv;
          fv.x = acc[mf][0][j] + bv[0];
          fv.y = acc[mf][1][j] + bv[1];
          fv.z = acc[mf][2][j] + bv[2];
          fv.w = acc[mf][3][j] + bv[3];
          *(float4*)((float*)Cout + (size_t)row * N + colb) = fv;
        } else {
          ushort4 st;
          st.x = f2bf(acc[mf][0][j] + bv[0]);
          st.y = f2bf(acc[mf][1][j] + bv[1]);
          st.z = f2bf(acc[mf][2][j] + bv[2]);
          st.w = f2bf(acc[mf][3][j] + bv[3]);
          *(ushort4*)((u16*)Cout + (size_t)row * N + colb) = st;
        }
      }
    }
  }
}

// Merged Q/K/V GEMMs: 768 blocks, 256 per GEMM.
__global__ __launch_bounds__(512, 2) void gemm8_qkv(const u16* __restrict__ Xb,
                                                    const u16* __restrict__ Yb,
                                                    const u16* __restrict__ Wqb,
                                                    const u16* __restrict__ Wkb,
                                                    const u16* __restrict__ Wvb,
                                                    const float* __restrict__ bq,
                                                    const float* __restrict__ bk,
                                                    const float* __restrict__ bv,
                                                    u16* __restrict__ Qb,
                                                    u16* __restrict__ Kb,
                                                    u16* __restrict__ VTb) {
  __shared__ u16 Al[2 * 16384];
  __shared__ u16 Bl[2 * 16384];
  const int sel = blockIdx.x >> 8, bid = blockIdx.x & 255;
  if (sel == 0)      gemm8_core<1>(bid, Xb, Wqb, bq, Qb, Al, Bl);
  else if (sel == 1) gemm8_core<1>(bid, Yb, Wkb, bk, Kb, Al, Bl);
  else               gemm8_core<2>(bid, Yb, Wvb, bv, VTb, Al, Bl);
}

__global__ __launch_bounds__(512, 2) void gemm8_out(const u16* __restrict__ A,
                                                    const u16* __restrict__ B,
                                                    const float* __restrict__ bias,
                                                    float* __restrict__ C) {
  __shared__ u16 Al[2 * 16384];
  __shared__ u16 Bl[2 * 16384];
  gemm8_core<0>(blockIdx.x, A, B, bias, C, Al, Bl);
}

// -------- fused attention (R17): K fragments GLOBAL->VGPR, LDS holds only Vs --------
// Six levers at the 142us plateau all kept the K LDS round-trip. That path costs
// 64KB LDS reads + 16KB writes + a lgkm drain per block-iteration (each of 4 waves
// reads the ENTIRE 16KB K tile). K frags are directly loadable: lanes {q,q+16,q+32,
// q+48} read contiguous 64B lines, L2-hot (16 blocks/XCD share each hb's K, 2MB<L2).
// kfr[16] prefetched one tile ahead (issued after QK releases the regs; coverage =
// softmax+PV+barrier >> L2 latency). Barriers now protect only Vs.
__global__ __launch_bounds__(256) void attn_kernel(const u16* __restrict__ Q,
                                                   const u16* __restrict__ Kf,
                                                   const u16* __restrict__ VT,
                                                   const float* __restrict__ adj,
                                                   u16* __restrict__ O) {
  __shared__ u16 Vs[256 * 32];    // V^T tile [d][key], 64B rows, sl ^= ((dr>>1)&3)
  const int tid = threadIdx.x, w = tid >> 6, l = tid & 63;
  const int g = l >> 4, q = l & 15;
  const int bid = blockIdx.x;
  const int xcd = bid & 7, idx = bid >> 3;           // 8 XCDs x 128 blocks
  const int b = xcd * 2 + (idx >> 6);                // 2 batches per XCD
  const int qb = (idx >> 2) & 15, h = idx & 3;       // qb sweeps, h fastest
  const int hb = h * 16 + b;
  const int q0 = qb * 64;
  const u16* qb_p = Q + ((size_t)hb * 1024 + q0 + w * 16) * 256;
  const u16* kb = Kf + (size_t)hb * 1024 * 256;
  const u16* vtb = VT + (size_t)hb * 256 * 1024;
  const float* adjr = adj + (size_t)b * 1024 * 1024 + (size_t)(q0 + w * 16 + q) * 1024;

  // V staging geometry
  const int vdr_b = tid >> 2;          // + i*64 -> V^T d-row 0..255
  const int vsl = tid & 3;             // 16B slot within 64B V row

  // Q fragments (B-operand of S^T): lane q=l&15, d = kk*32 + g*8 + j
  short8_t qf[8];
#pragma unroll
  for (int kk = 0; kk < 8; ++kk)
    qf[kk] = *(const short8_t*)(qb_p + (size_t)q * 256 + kk * 32 + g * 8);

  f32x4 o[16];  // O^T accum: lane holds O[q][d], d = n*16 + g*4 + r
#pragma unroll
  for (int n = 0; n < 16; ++n) o[n] = fz4();
  float mrun = -1e30f, lrun = 0.f;

  short8_t kfr[16];   // K fragments, direct A-operand layout (prefetched 1 tile)
  short8_t vst[4];    // reg-staged next V tile

#define LOADK(ktt)                                                                 \
  {                                                                                \
    _Pragma("unroll") for (int f_ = 0; f_ < 2; ++f_)                               \
    _Pragma("unroll") for (int kk_ = 0; kk_ < 8; ++kk_)                            \
      kfr[f_ * 8 + kk_] = *(const short8_t*)(kb +                                  \
          (size_t)((ktt) * 32 + f_ * 16 + q) * 256 + kk_ * 32 + g * 8);            \
  }
#define LOADV(ktt)                                                                 \
  {                                                                                \
    _Pragma("unroll") for (int i_ = 0; i_ < 4; ++i_) {                             \
      const int dr_ = i_ * 64 + vdr_b;                                             \
      vst[i_] = *(const short8_t*)(vtb + (size_t)dr_ * 1024 + (ktt) * 32 +         \
                                   vsl * 8);                                       \
    }                                                                              \
  }
#define WRITEV()                                                                   \
  {                                                                                \
    _Pragma("unroll") for (int i_ = 0; i_ < 4; ++i_) {                             \
      const int dr_ = i_ * 64 + vdr_b;                                             \
      *(short8_t*)((char*)Vs + dr_ * 64 + ((vsl ^ ((dr_ >> 1) & 3)) * 16)) = vst[i_];\
    }                                                                              \
  }

  // prologue: K frags tile 0 -> regs; V tile 0 -> LDS; adj tile 0
  LOADK(0);
  LOADV(0);
  float4 a0 = *(const float4*)(adjr + 0 * 32 + 0 * 16 + g * 4);
  float4 a1 = *(const float4*)(adjr + 0 * 32 + 1 * 16 + g * 4);
  WRITEV();
  __syncthreads();

  for (int kt = 0; kt < 32; ++kt) {
    // S^T = K Q^T : 4 independent chains of 4 MFMA, all operands in VGPRs
    f32x4 s[2];
    {
      f32x4 c00 = fz4(), c01 = fz4(), c10 = fz4(), c11 = fz4();
      __builtin_amdgcn_s_setprio(1);
#pragma unroll
      for (int kk = 0; kk < 4; ++kk) {
        c00 = __builtin_amdgcn_mfma_f32_16x16x32_bf16(kfr[kk], qf[kk], c00, 0, 0, 0);
        c01 = __builtin_amdgcn_mfma_f32_16x16x32_bf16(kfr[kk + 4], qf[kk + 4], c01, 0, 0, 0);
        c10 = __builtin_amdgcn_mfma_f32_16x16x32_bf16(kfr[8 + kk], qf[kk], c10, 0, 0, 0);
        c11 = __builtin_amdgcn_mfma_f32_16x16x32_bf16(kfr[12 + kk], qf[kk + 4], c11, 0, 0, 0);
      }
      __builtin_amdgcn_s_setprio(0);
      s[0] = c00 + c01;
      s[1] = c10 + c11;
    }

    // prefetch next tile: K frags (WAR on kfr after QK), V regs, adj
    float4 n0v = a0, n1v = a1;
    if (kt < 31) {
      LOADK(kt + 1);
      LOADV(kt + 1);
      n0v = *(const float4*)(adjr + (kt + 1) * 32 + 0 * 16 + g * 4);
      n1v = *(const float4*)(adjr + (kt + 1) * 32 + 1 * 16 + g * 4);
    }

    // scale + adj (vectorized float4 per frag)
#pragma unroll
    for (int j = 0; j < 4; ++j) {
      s[0][j] = s[0][j] * 0.03125f + ((const float*)&a0)[j];
      s[1][j] = s[1][j] * 0.03125f + ((const float*)&a1)[j];
    }

    // per-lane online softmax: 8 local values + reduce across g (xor 16,32)
    float pmax = s[0][0];
#pragma unroll
    for (int j = 1; j < 4; ++j) pmax = fmaxf(pmax, s[0][j]);
#pragma unroll
    for (int j = 0; j < 4; ++j) pmax = fmaxf(pmax, s[1][j]);
    pmax = fmaxf(pmax, __shfl_xor(pmax, 16));
    pmax = fmaxf(pmax, __shfl_xor(pmax, 32));

    if (!__all(pmax - mrun <= 8.0f)) {          // T13 defer-max
      const float mn = fmaxf(mrun, pmax);
      const float al = __expf(mrun - mn);
      mrun = mn;
      lrun *= al;
#pragma unroll
      for (int n = 0; n < 16; ++n)
#pragma unroll
        for (int r = 0; r < 4; ++r) o[n][r] *= al;
    }

    float sum = 0.f;
#pragma unroll
    for (int f = 0; f < 2; ++f)
#pragma unroll
      for (int j = 0; j < 4; ++j) {
        const float p = __expf(s[f][j] - mrun);
        s[f][j] = p;
        sum += p;
      }
    sum += __shfl_xor(sum, 16);
    sum += __shfl_xor(sum, 32);
    lrun += sum;

    // ---- T12: P^T -> MFMA B-operand fully in-register ----
    uint32_t W00, W01, W10, W11;
    asm("v_cvt_pk_bf16_f32 %0, %1, %2" : "=v"(W00) : "v"(s[0][0]), "v"(s[0][1]));
    asm("v_cvt_pk_bf16_f32 %0, %1, %2" : "=v"(W01) : "v"(s[0][2]), "v"(s[0][3]));
    asm("v_cvt_pk_bf16_f32 %0, %1, %2" : "=v"(W10) : "v"(s[1][0]), "v"(s[1][1]));
    asm("v_cvt_pk_bf16_f32 %0, %1, %2" : "=v"(W11) : "v"(s[1][2]), "v"(s[1][3]));
    const uint32_t sA0 = (g < 2) ? W00 : W10;   // W[g>>1][0]
    const uint32_t sA1 = (g < 2) ? W01 : W11;   // W[g>>1][1]
    const uint32_t sB0 = (g < 2) ? W10 : W00;   // W[(g>>1)^1][0]
    const uint32_t sB1 = (g < 2) ? W11 : W01;   // W[(g>>1)^1][1]
    const uint32_t A0 = (uint32_t)__shfl_xor((int)sA0, 16);
    const uint32_t A1 = (uint32_t)__shfl_xor((int)sA1, 16);
    const uint32_t B0 = (uint32_t)__shfl_xor((int)sB0, 32);
    const uint32_t B1 = (uint32_t)__shfl_xor((int)sB1, 32);
    const uint32_t C0 = (uint32_t)__shfl_xor((int)sB0, 48);
    const uint32_t C1 = (uint32_t)__shfl_xor((int)sB1, 48);
    union { uint32_t u[4]; short8_t v; } pu;
    pu.u[0] = (g == 0) ? W00 : (g == 1) ? C0 : (g == 2) ? B0 : A0;
    pu.u[1] = (g == 0) ? W01 : (g == 1) ? C1 : (g == 2) ? B1 : A1;
    pu.u[2] = (g == 0) ? A0 : (g == 1) ? B0 : (g == 2) ? C0 : W10;
    pu.u[3] = (g == 0) ? A1 : (g == 1) ? B1 : (g == 2) ? C1 : W11;
    const short8_t pa = pu.v;

    // O^T += V^T P^T : 16 d-frags, one k-step (K=32 keys)
    __builtin_amdgcn_s_setprio(1);
#pragma unroll
    for (int n = 0; n < 16; ++n) {
      const int dr = n * 16 + q;
      const int sl = g ^ ((dr >> 1) & 3);
      short8_t vf = *(const short8_t*)((const char*)Vs + dr * 64 + sl * 16);
      o[n] = __builtin_amdgcn_mfma_f32_16x16x32_bf16(vf, pa, o[n], 0, 0, 0);
    }
    __builtin_amdgcn_s_setprio(0);

    if (kt < 31) {
      __syncthreads();             // all waves done reading Vs
      WRITEV();                    // compiler inserts vmcnt for reg deps
      __syncthreads();             // writes visible
    }
    a0 = n0v; a1 = n1v;
  }
#undef LOADK
#undef LOADV
#undef WRITEV

  // epilogue: normalize, packed 8B stores; lane owns row q, d = n*16+g*4+r
  const float inv = 1.0f / lrun;
  u16* ob = O + ((size_t)hb * 1024 + q0 + w * 16 + q) * 256;
#pragma unroll
  for (int n = 0; n < 16; ++n) {
    ushort4 st;
    st.x = f2bf(o[n][0] * inv); st.y = f2bf(o[n][1] * inv);
    st.z = f2bf(o[n][2] * inv); st.w = f2bf(o[n][3] * inv);
    *(ushort4*)(ob + n * 16 + g * 4) = st;
  }
}

extern "C" void kernel_launch(void* const* d_in, const int* in_sizes, int n_in,
                              void* d_out, int out_size, void* d_ws, size_t ws_size,
                              hipStream_t stream) {
  (void)in_sizes; (void)n_in; (void)out_size; (void)ws_size;
  const float* x   = (const float*)d_in[0];
  const float* y   = (const float*)d_in[1];
  const float* adj = (const float*)d_in[2];
  const float* Wq  = (const float*)d_in[3];
  const float* bq  = (const float*)d_in[4];
  const float* Wk  = (const float*)d_in[5];
  const float* bk  = (const float*)d_in[6];
  const float* Wv  = (const float*)d_in[7];
  const float* bv  = (const float*)d_in[8];
  const float* Wo  = (const float*)d_in[9];
  const float* bo  = (const float*)d_in[10];

  char* ws = (char*)d_ws;
  const size_t MB = 1ull << 20;
  u16* Xb  = (u16*)(ws + 0);        // 32MB, reused as Tmp after Q GEMM
  u16* Yb  = (u16*)(ws + 32 * MB);  // 32MB
  u16* Wqb = (u16*)(ws + 64 * MB);  // 2MB each
  u16* Wkb = (u16*)(ws + 66 * MB);
  u16* Wvb = (u16*)(ws + 68 * MB);
  u16* Wob = (u16*)(ws + 70 * MB);
  u16* Qb  = (u16*)(ws + 72 * MB);  // 32MB
  u16* Kb  = (u16*)(ws + 104 * MB);
  u16* VTb = (u16*)(ws + 168 * MB); // V GEMM writes transposed layout directly
  u16* Tmp = Xb;

  cast_all<<<36864, 256, 0, stream>>>(x, y, Wq, Wk, Wv, Wo,
                                      Xb, Yb, Wqb, Wkb, Wvb, Wob);

  gemm8_qkv<<<768, 512, 0, stream>>>(Xb, Yb, Wqb, Wkb, Wvb, bq, bk, bv, Qb, Kb, VTb);

  attn_kernel<<<1024, 256, 0, stream>>>(Qb, Kb, VTb, adj, Tmp);

  gemm8_out<<<256, 512, 0, stream>>>(Tmp, Wob, bo, (float*)d_out);
}

// Round 18
// 332.290 us; speedup vs baseline: 1.6509x; 1.6509x over previous
//
#include <hip/hip_runtime.h>
#include <stdint.h>
#include <string.h>

typedef unsigned short u16;
typedef __attribute__((ext_vector_type(8))) short short8_t;   // 8 x bf16 (4 VGPRs)
typedef __attribute__((ext_vector_type(4))) float f32x4;

typedef const __attribute__((address_space(1))) void GV;
typedef __attribute__((address_space(3))) void LV;

__device__ __forceinline__ void gload_lds16(const void* g, void* l) {
  // async global->LDS, 16B per lane; LDS dest is wave-uniform base + lane*16
  __builtin_amdgcn_global_load_lds((GV*)g, (LV*)l, 16, 0, 0);
}

__device__ __forceinline__ u16 f2bf(float f) {
  union { float f; uint32_t u; } v; v.f = f;
  return (u16)((v.u + 0x7FFFu + ((v.u >> 16) & 1u)) >> 16);  // RNE
}

__device__ __forceinline__ f32x4 fz4() { f32x4 v = {0.f, 0.f, 0.f, 0.f}; return v; }

// ------------- all casts fp32 -> bf16 (4 elems/thread) in ONE launch -------------
__global__ __launch_bounds__(256) void cast_all(const float* __restrict__ x,
                                                const float* __restrict__ y,
                                                const float* __restrict__ w0,
                                                const float* __restrict__ w1,
                                                const float* __restrict__ w2,
                                                const float* __restrict__ w3,
                                                u16* __restrict__ xo,
                                                u16* __restrict__ yo,
                                                u16* __restrict__ o0,
                                                u16* __restrict__ o1,
                                                u16* __restrict__ o2,
                                                u16* __restrict__ o3) {
  const int bid = blockIdx.x;
  const float* in;
  u16* out;
  int off;
  if (bid < 32768) {
    in = (bid < 16384) ? x : y;
    out = (bid < 16384) ? xo : yo;
    off = bid & 16383;
  } else {
    const int s = (bid - 32768) >> 10;
    in = s == 0 ? w0 : s == 1 ? w1 : s == 2 ? w2 : w3;
    out = s == 0 ? o0 : s == 1 ? o1 : s == 2 ? o2 : o3;
    off = (bid - 32768) & 1023;
  }
  int i = (off * 256 + threadIdx.x) * 4;
  float4 v = *(const float4*)(in + i);
  ushort4 o;
  o.x = f2bf(v.x); o.y = f2bf(v.y); o.z = f2bf(v.z); o.w = f2bf(v.w);
  *(ushort4*)(out + i) = o;
}

// ======== 256x256 8-phase GEMM core (T2+T3+T4+T5): C = A[M,K]*B[N,K]^T + bias ========
// R14 EXACT core (measured session-best, 332.3us total). R11 T1 mapping: xcd=bid&7,
// n fastest, contiguous 8-m-tile range per XCD. Per-mode COLUMN PERMUTATION for
// vector epilogue stores:
//  MODE 0/1 linear: phys(u) = n0 + (u&0xC0) + (u&15)*4 + ((u>>4)&3)
//  MODE 2 VT[hb][d][t]: phys(u) = ((u>>4)&3)*256 + nt*64 + ((u>>6)&3)*16 + (u&15)
//  MODE 3 = MODE 1 with (acc+bias)*0.03125 (exact 2^-5 exponent shift — folds the
//           softmax scale into Q; bf16 rounding bit-identical).
template <int MODE>
__device__ __forceinline__ void gemm8_core(int bid, const u16* __restrict__ A,
                                           const u16* __restrict__ B,
                                           const float* __restrict__ bias,
                                           void* __restrict__ Cout,
                                           u16* Al, u16* Bl) {
  const int N = 1024, K = 1024;
  const int tid = threadIdx.x, w = tid >> 6, l = tid & 63;
  const int g = l >> 4, q = l & 15;
  const int xcd = bid & 7;
  const int nt = (bid >> 3) & 3;                 // n fastest within XCD
  const int mt = xcd * 8 + (bid >> 5);           // contiguous m-range per XCD
  const int n0 = nt * 256, m0 = mt * 256;
  const int NT = K >> 6;
  const int ah = w >> 2;            // this wave's A half
  const int bh = (w & 3) >> 1;      // this wave's B half
  const int brow0 = ((w & 3) & 1) * 64;

  // logical B row u (0..255) -> physical B row (column of C)
#define BROW(u)                                                                   \
  (MODE == 2 ? ((((u) >> 4) & 3) * 256 + nt * 64 + (((u) >> 6) & 3) * 16 + ((u) & 15)) \
             : (n0 + (((u) & 0xC0) | (((u) & 15) << 2) | (((u) >> 4) & 3))))

#define STAGE_A(S, half)                                                          \
  {                                                                               \
    _Pragma("unroll") for (int j_ = 0; j_ < 2; ++j_) {                            \
      const int idx_ = j_ * 512 + tid;                                            \
      const int row_ = idx_ >> 3;                                                 \
      const int sl_ = (idx_ & 7) ^ (((idx_ >> 5) & 1) << 1);                      \
      gload_lds16(A + (size_t)(m0 + (half) * 128 + row_) * K + (S) * 64 + sl_ * 8,\
                  Al + ((S) & 1) * 16384 + (half) * 8192 + (j_ * 512 + w * 64) * 8);\
    }                                                                             \
  }
#define STAGE_B(S, half)                                                          \
  {                                                                               \
    _Pragma("unroll") for (int j_ = 0; j_ < 2; ++j_) {                            \
      const int idx_ = j_ * 512 + tid;                                            \
      const int row_ = idx_ >> 3;                                                 \
      const int sl_ = (idx_ & 7) ^ (((idx_ >> 5) & 1) << 1);                      \
      const int pr_ = BROW((half) * 128 + row_);                                  \
      gload_lds16(B + (size_t)pr_ * K + (S) * 64 + sl_ * 8,                       \
                  Bl + ((S) & 1) * 16384 + (half) * 8192 + (j_ * 512 + w * 64) * 8);\
    }                                                                             \
  }

  f32x4 acc[8][4];
#pragma unroll
  for (int i = 0; i < 8; ++i)
#pragma unroll
    for (int n = 0; n < 4; ++n) acc[i][n] = fz4();

  // bias per lane (epilogue operand), load early; index = physical column
  const int wc = (w & 3) * 64;
  float bv[4];
#pragma unroll
  for (int nf = 0; nf < 4; ++nf) bv[nf] = bias[BROW(wc + nf * 16 + q)];

  // prologue: stage tiles 0 and 1 fully (16 loads/thread)
  STAGE_A(0, 0); STAGE_A(0, 1); STAGE_B(0, 0); STAGE_B(0, 1);
  STAGE_A(1, 0); STAGE_A(1, 1); STAGE_B(1, 0); STAGE_B(1, 1);
  asm volatile("s_waitcnt vmcnt(8)");          // tile 0 landed; tile 1 in flight
  __builtin_amdgcn_s_barrier();

  short8_t bfr[4][2];
  for (int S = 0; S < NT; ++S) {
    const int bs = (S & 1) * 16384;
#pragma unroll
    for (int p = 0; p < 4; ++p) {
      // ---- ds_read register subtiles ----
      short8_t afr[2][2];
#pragma unroll
      for (int mi = 0; mi < 2; ++mi)
#pragma unroll
        for (int kk = 0; kk < 2; ++kk) {
          const int r = (2 * p + mi) * 16 + q;
          afr[mi][kk] = *(const short8_t*)(Al + bs + ah * 8192 + r * 64 +
                                           ((kk * 4 + g) ^ (((r >> 2) & 1) << 1)) * 8);
        }
      if (p == 0) {
#pragma unroll
        for (int nf = 0; nf < 4; ++nf)
#pragma unroll
          for (int kk = 0; kk < 2; ++kk) {
            const int r = brow0 + nf * 16 + q;
            bfr[nf][kk] = *(const short8_t*)(Bl + bs + bh * 8192 + r * 64 +
                                             ((kk * 4 + g) ^ (((r >> 2) & 1) << 1)) * 8);
          }
      }
      // ---- issue one half-tile stage ----
      if (p == 0 && S >= 1 && S + 1 < NT) STAGE_A(S + 1, 0);
      if (p == 1 && S >= 1 && S + 1 < NT) STAGE_A(S + 1, 1);
      if (p == 2 && S + 2 < NT) STAGE_B(S + 2, 0);
      if (p == 3 && S + 2 < NT) STAGE_B(S + 2, 1);
      // ---- counted vmcnt once per K-tile, fencing tile S+1's reads ----
      if (p == 3) {
        if (S == NT - 2) { asm volatile("s_waitcnt vmcnt(0)"); }
        else if (S < NT - 2) { asm volatile("s_waitcnt vmcnt(4)"); }
      }
      __builtin_amdgcn_s_barrier();
      asm volatile("s_waitcnt lgkmcnt(0)" ::: "memory");
      __builtin_amdgcn_sched_barrier(0);
      __builtin_amdgcn_s_setprio(1);
#pragma unroll
      for (int nf = 0; nf < 4; ++nf)
#pragma unroll
        for (int mi = 0; mi < 2; ++mi)
#pragma unroll
          for (int kk = 0; kk < 2; ++kk)
            acc[2 * p + mi][nf] = __builtin_amdgcn_mfma_f32_16x16x32_bf16(
                afr[mi][kk], bfr[nf][kk], acc[2 * p + mi][nf], 0, 0, 0);
      __builtin_amdgcn_s_setprio(0);
      __builtin_amdgcn_s_barrier();
    }
  }
#undef STAGE_A
#undef STAGE_B
#undef BROW

  // epilogue: bias (+optional exact 2^-5 scale) + VECTOR stores
  const int wr = (w >> 2) * 128;
  if (MODE == 2) {
    const int dvt = nt * 64 + (w & 3) * 16 + q;   // d index (c&255)
#pragma unroll
    for (int mf = 0; mf < 8; ++mf) {
#pragma unroll
      for (int j = 0; j < 4; ++j) {
        const int row = m0 + wr + mf * 16 + g * 4 + j;
        ushort4 st;
        st.x = f2bf(acc[mf][0][j] + bv[0]);
        st.y = f2bf(acc[mf][1][j] + bv[1]);
        st.z = f2bf(acc[mf][2][j] + bv[2]);
        st.w = f2bf(acc[mf][3][j] + bv[3]);
        *(ushort4*)((u16*)Cout + (((size_t)(row >> 8)) << 18) +
                    (((size_t)dvt) << 10) + ((row & 255) << 2)) = st;
      }
    }
  } else {
    const int colb = n0 + wc + q * 4;             // 4 consecutive physical cols
    const float sc = (MODE == 3) ? 0.03125f : 1.0f;
#pragma unroll
    for (int mf = 0; mf < 8; ++mf) {
#pragma unroll
      for (int j = 0; j < 4; ++j) {
        const int row = m0 + wr + mf * 16 + g * 4 + j;
        if (MODE == 0) {
          float4 fv;
          fv.x = acc[mf][0][j] + bv[0];
          fv.y = acc[mf][1][j] + bv[1];
          fv.z = acc[mf][2][j] + bv[2];
          fv.w = acc[mf][3][j] + bv[3];
          *(float4*)((float*)Cout + (size_t)row * N + colb) = fv;
        } else {
          ushort4 st;
          st.x = f2bf((acc[mf][0][j] + bv[0]) * sc);
          st.y = f2bf((acc[mf][1][j] + bv[1]) * sc);
          st.z = f2bf((acc[mf][2][j] + bv[2]) * sc);
          st.w = f2bf((acc[mf][3][j] + bv[3]) * sc);
          *(ushort4*)((u16*)Cout + (size_t)row * N + colb) = st;
        }
      }
    }
  }
}

// Merged Q/K/V GEMMs: 768 blocks, 256 per GEMM. Q uses MODE 3 (pre-scaled by 2^-5).
__global__ __launch_bounds__(512, 2) void gemm8_qkv(const u16* __restrict__ Xb,
                                                    const u16* __restrict__ Yb,
                                                    const u16* __restrict__ Wqb,
                                                    const u16* __restrict__ Wkb,
                                                    const u16* __restrict__ Wvb,
                                                    const float* __restrict__ bq,
                                                    const float* __restrict__ bk,
                                                    const float* __restrict__ bv,
                                                    u16* __restrict__ Qb,
                                                    u16* __restrict__ Kb,
                                                    u16* __restrict__ VTb) {
  __shared__ u16 Al[2 * 16384];
  __shared__ u16 Bl[2 * 16384];
  const int sel = blockIdx.x >> 8, bid = blockIdx.x & 255;
  if (sel == 0)      gemm8_core<3>(bid, Xb, Wqb, bq, Qb, Al, Bl);
  else if (sel == 1) gemm8_core<1>(bid, Yb, Wkb, bk, Kb, Al, Bl);
  else               gemm8_core<2>(bid, Yb, Wvb, bv, VTb, Al, Bl);
}

__global__ __launch_bounds__(512, 2) void gemm8_out(const u16* __restrict__ A,
                                                    const u16* __restrict__ B,
                                                    const float* __restrict__ bias,
                                                    float* __restrict__ C) {
  __shared__ u16 Al[2 * 16384];
  __shared__ u16 Bl[2 * 16384];
  gemm8_core<0>(blockIdx.x, A, B, bias, C, Al, Bl);
}

// -------- fused attention: R14 EXACT structure (KVBLK=32, T14 reg-staged, T12) --------
// (session-best measured config; R17's K-from-global reverted — global latency in the
// serial chain was 2.5x worse). Only change vs R14: Q arrives pre-scaled by 2^-5, so
// softmax uses s + adj directly (no per-iteration multiply).
__global__ __launch_bounds__(256) void attn_kernel(const u16* __restrict__ Q,
                                                   const u16* __restrict__ Kf,
                                                   const u16* __restrict__ VT,
                                                   const float* __restrict__ adj,
                                                   u16* __restrict__ O) {
  __shared__ u16 Ks[32 * 256];    // K tile [key][d], 512B rows, slot ^= (row&7)
  __shared__ u16 Vs[256 * 32];    // V^T tile [d][key], 64B rows, sl ^= ((dr>>1)&3)
  const int tid = threadIdx.x, w = tid >> 6, l = tid & 63;
  const int g = l >> 4, q = l & 15;
  const int bid = blockIdx.x;
  const int xcd = bid & 7, idx = bid >> 3;           // 8 XCDs x 128 blocks
  const int b = xcd * 2 + (idx >> 6);                // 2 batches per XCD
  const int qb = (idx >> 2) & 15, h = idx & 3;       // qb sweeps, h fastest
  const int hb = h * 16 + b;
  const int q0 = qb * 64;
  const u16* qb_p = Q + ((size_t)hb * 1024 + q0 + w * 16) * 256;
  const u16* kb = Kf + (size_t)hb * 1024 * 256;
  const u16* vtb = VT + (size_t)hb * 256 * 1024;
  const float* adjr = adj + (size_t)b * 1024 * 1024 + (size_t)(q0 + w * 16 + q) * 1024;

  // per-thread staging geometry (constant across iterations)
  const int krow_b = tid >> 5;         // + i*8 -> K row 0..31
  const int kslot = tid & 31;          // 16B slot within 512B K row
  const int vdr_b = tid >> 2;          // + i*64 -> V^T d-row 0..255
  const int vsl = tid & 3;             // 16B slot within 64B V row

  // Q fragments (B-operand of S^T): lane q=l&15, d = kk*32 + g*8 + j
  short8_t qf[8];
#pragma unroll
  for (int kk = 0; kk < 8; ++kk)
    qf[kk] = *(const short8_t*)(qb_p + (size_t)q * 256 + kk * 32 + g * 8);

  f32x4 o[16];  // O^T accum: lane holds O[q][d], d = n*16 + g*4 + r
#pragma unroll
  for (int n = 0; n < 16; ++n) o[n] = fz4();
  float mrun = -1e30f, lrun = 0.f;

  short8_t kst[4], vst[4];   // reg-staged next tile (+32 VGPR)

#define LOADREGS(ktt)                                                              \
  {                                                                                \
    _Pragma("unroll") for (int i_ = 0; i_ < 4; ++i_) {                             \
      const int row_ = i_ * 8 + krow_b;                                            \
      kst[i_] = *(const short8_t*)(kb + (size_t)((ktt) * 32 + row_) * 256 +        \
                                   kslot * 8);                                     \
    }                                                                              \
    _Pragma("unroll") for (int i_ = 0; i_ < 4; ++i_) {                             \
      const int dr_ = i_ * 64 + vdr_b;                                             \
      vst[i_] = *(const short8_t*)(vtb + (size_t)dr_ * 1024 + (ktt) * 32 +         \
                                   vsl * 8);                                       \
    }                                                                              \
  }
#define WRITEREGS()                                                                \
  {                                                                                \
    _Pragma("unroll") for (int i_ = 0; i_ < 4; ++i_) {                             \
      const int row_ = i_ * 8 + krow_b;                                            \
      *(short8_t*)((char*)Ks + row_ * 512 + ((kslot ^ (row_ & 7)) * 16)) = kst[i_];\
    }                                                                              \
    _Pragma("unroll") for (int i_ = 0; i_ < 4; ++i_) {                             \
      const int dr_ = i_ * 64 + vdr_b;                                             \
      *(short8_t*)((char*)Vs + dr_ * 64 + ((vsl ^ ((dr_ >> 1) & 3)) * 16)) = vst[i_];\
    }                                                                              \
  }

  // prologue: tile 0 regs -> LDS; adj tile 0 prefetch
  LOADREGS(0);
  float4 a0 = *(const float4*)(adjr + 0 * 32 + 0 * 16 + g * 4);
  float4 a1 = *(const float4*)(adjr + 0 * 32 + 1 * 16 + g * 4);
  WRITEREGS();
  __syncthreads();

  for (int kt = 0; kt < 32; ++kt) {
    float4 n0v = a0, n1v = a1;
    if (kt < 31) {
      LOADREGS(kt + 1);            // issue early: latency hides under QK+sm+PV
      n0v = *(const float4*)(adjr + (kt + 1) * 32 + 0 * 16 + g * 4);
      n1v = *(const float4*)(adjr + (kt + 1) * 32 + 1 * 16 + g * 4);
    }

    // S^T = K Q^T : 2 key-frags x 8 d-steps. lane: q=l&15, k = f*16 + g*4 + r
    f32x4 s[2];
    __builtin_amdgcn_s_setprio(1);
#pragma unroll
    for (int f = 0; f < 2; ++f) {
      f32x4 a = fz4();
      const int row = f * 16 + q;
      const char* kr = (const char*)Ks + row * 512;
#pragma unroll
      for (int kk = 0; kk < 8; ++kk) {
        const int cb = kk * 64 + g * 16;
        short8_t kfr = *(const short8_t*)(kr + (cb ^ ((row & 7) << 4)));
        a = __builtin_amdgcn_mfma_f32_16x16x32_bf16(kfr, qf[kk], a, 0, 0, 0);
      }
      s[f] = a;
    }
    __builtin_amdgcn_s_setprio(0);

    // + adj (scale already folded into Q at the Q GEMM — exact 2^-5)
#pragma unroll
    for (int j = 0; j < 4; ++j) {
      s[0][j] = s[0][j] + ((const float*)&a0)[j];
      s[1][j] = s[1][j] + ((const float*)&a1)[j];
    }

    // per-lane online softmax: 8 local values + reduce across g (xor 16,32)
    float pmax = s[0][0];
#pragma unroll
    for (int j = 1; j < 4; ++j) pmax = fmaxf(pmax, s[0][j]);
#pragma unroll
    for (int j = 0; j < 4; ++j) pmax = fmaxf(pmax, s[1][j]);
    pmax = fmaxf(pmax, __shfl_xor(pmax, 16));
    pmax = fmaxf(pmax, __shfl_xor(pmax, 32));

    if (!__all(pmax - mrun <= 8.0f)) {          // T13 defer-max
      const float mn = fmaxf(mrun, pmax);
      const float al = __expf(mrun - mn);
      mrun = mn;
      lrun *= al;
#pragma unroll
      for (int n = 0; n < 16; ++n)
#pragma unroll
        for (int r = 0; r < 4; ++r) o[n][r] *= al;
    }

    float sum = 0.f;
#pragma unroll
    for (int f = 0; f < 2; ++f)
#pragma unroll
      for (int j = 0; j < 4; ++j) {
        const float p = __expf(s[f][j] - mrun);
        s[f][j] = p;
        sum += p;
      }
    sum += __shfl_xor(sum, 16);
    sum += __shfl_xor(sum, 32);
    lrun += sum;

    // ---- T12: P^T -> MFMA B-operand fully in-register ----
    uint32_t W00, W01, W10, W11;
    asm("v_cvt_pk_bf16_f32 %0, %1, %2" : "=v"(W00) : "v"(s[0][0]), "v"(s[0][1]));
    asm("v_cvt_pk_bf16_f32 %0, %1, %2" : "=v"(W01) : "v"(s[0][2]), "v"(s[0][3]));
    asm("v_cvt_pk_bf16_f32 %0, %1, %2" : "=v"(W10) : "v"(s[1][0]), "v"(s[1][1]));
    asm("v_cvt_pk_bf16_f32 %0, %1, %2" : "=v"(W11) : "v"(s[1][2]), "v"(s[1][3]));
    const uint32_t sA0 = (g < 2) ? W00 : W10;   // W[g>>1][0]
    const uint32_t sA1 = (g < 2) ? W01 : W11;   // W[g>>1][1]
    const uint32_t sB0 = (g < 2) ? W10 : W00;   // W[(g>>1)^1][0]
    const uint32_t sB1 = (g < 2) ? W11 : W01;   // W[(g>>1)^1][1]
    const uint32_t A0 = (uint32_t)__shfl_xor((int)sA0, 16);
    const uint32_t A1 = (uint32_t)__shfl_xor((int)sA1, 16);
    const uint32_t B0 = (uint32_t)__shfl_xor((int)sB0, 32);
    const uint32_t B1 = (uint32_t)__shfl_xor((int)sB1, 32);
    const uint32_t C0 = (uint32_t)__shfl_xor((int)sB0, 48);
    const uint32_t C1 = (uint32_t)__shfl_xor((int)sB1, 48);
    union { uint32_t u[4]; short8_t v; } pu;
    pu.u[0] = (g == 0) ? W00 : (g == 1) ? C0 : (g == 2) ? B0 : A0;
    pu.u[1] = (g == 0) ? W01 : (g == 1) ? C1 : (g == 2) ? B1 : A1;
    pu.u[2] = (g == 0) ? A0 : (g == 1) ? B0 : (g == 2) ? C0 : W10;
    pu.u[3] = (g == 0) ? A1 : (g == 1) ? B1 : (g == 2) ? C1 : W11;
    const short8_t pa = pu.v;

    // O^T += V^T P^T : 16 d-frags, one k-step (K=32 keys)
    __builtin_amdgcn_s_setprio(1);
#pragma unroll
    for (int n = 0; n < 16; ++n) {
      const int dr = n * 16 + q;
      const int sl = g ^ ((dr >> 1) & 3);
      short8_t vf = *(const short8_t*)((const char*)Vs + dr * 64 + sl * 16);
      o[n] = __builtin_amdgcn_mfma_f32_16x16x32_bf16(vf, pa, o[n], 0, 0, 0);
    }
    __builtin_amdgcn_s_setprio(0);

    if (kt < 31) {
      __syncthreads();             // all waves done reading Ks/Vs
      WRITEREGS();                 // compiler inserts vmcnt for reg deps
      __syncthreads();             // writes visible
    }
    a0 = n0v; a1 = n1v;
  }
#undef LOADREGS
#undef WRITEREGS

  // epilogue: normalize, packed 8B stores; lane owns row q, d = n*16+g*4+r
  const float inv = 1.0f / lrun;
  u16* ob = O + ((size_t)hb * 1024 + q0 + w * 16 + q) * 256;
#pragma unroll
  for (int n = 0; n < 16; ++n) {
    ushort4 st;
    st.x = f2bf(o[n][0] * inv); st.y = f2bf(o[n][1] * inv);
    st.z = f2bf(o[n][2] * inv); st.w = f2bf(o[n][3] * inv);
    *(ushort4*)(ob + n * 16 + g * 4) = st;
  }
}

extern "C" void kernel_launch(void* const* d_in, const int* in_sizes, int n_in,
                              void* d_out, int out_size, void* d_ws, size_t ws_size,
                              hipStream_t stream) {
  (void)in_sizes; (void)n_in; (void)out_size; (void)ws_size;
  const float* x   = (const float*)d_in[0];
  const float* y   = (const float*)d_in[1];
  const float* adj = (const float*)d_in[2];
  const float* Wq  = (const float*)d_in[3];
  const float* bq  = (const float*)d_in[4];
  const float* Wk  = (const float*)d_in[5];
  const float* bk  = (const float*)d_in[6];
  const float* Wv  = (const float*)d_in[7];
  const float* bv  = (const float*)d_in[8];
  const float* Wo  = (const float*)d_in[9];
  const float* bo  = (const float*)d_in[10];

  char* ws = (char*)d_ws;
  const size_t MB = 1ull << 20;
  u16* Xb  = (u16*)(ws + 0);        // 32MB, reused as Tmp after Q GEMM
  u16* Yb  = (u16*)(ws + 32 * MB);  // 32MB
  u16* Wqb = (u16*)(ws + 64 * MB);  // 2MB each
  u16* Wkb = (u16*)(ws + 66 * MB);
  u16* Wvb = (u16*)(ws + 68 * MB);
  u16* Wob = (u16*)(ws + 70 * MB);
  u16* Qb  = (u16*)(ws + 72 * MB);  // 32MB
  u16* Kb  = (u16*)(ws + 104 * MB);
  u16* VTb = (u16*)(ws + 168 * MB); // V GEMM writes transposed layout directly
  u16* Tmp = Xb;

  cast_all<<<36864, 256, 0, stream>>>(x, y, Wq, Wk, Wv, Wo,
                                      Xb, Yb, Wqb, Wkb, Wvb, Wob);

  gemm8_qkv<<<768, 512, 0, stream>>>(Xb, Yb, Wqb, Wkb, Wvb, bq, bk, bv, Qb, Kb, VTb);

  attn_kernel<<<1024, 256, 0, stream>>>(Qb, Kb, VTb, adj, Tmp);

  gemm8_out<<<256, 512, 0, stream>>>(Tmp, Wob, bo, (float*)d_out);
}